// Round 12
// baseline (689.259 us; speedup 1.0000x reference)
//
#include <hip/hip_runtime.h>
#include <hip/hip_fp16.h>
#include <cstdint>

// MessagePassing — FUSED MFMA edge-MLP + aggregation (w stays in LDS),
// tiled node_pre / post. N=20000, E=320000. CS=64, CV=32, CM=96, WN=192.

#define CS 64
#define CV 32
#define CM 96
#define WN 192
#define FCH 64
#define WPAD 72     // padded K-stride (halfs) for LDS weight tiles
#define NB 8        // nodes per fused block
#define WT_STR 68   // wT slot-stride in halfs (136 B: 8B-aligned, bank-friendly)

using f16x8 = __attribute__((ext_vector_type(8))) _Float16;
using f32x4 = __attribute__((ext_vector_type(4))) float;

__device__ __forceinline__ float siluf(float x){ return x / (1.f + __expf(-x)); }

constexpr float INV8       = 0.125f;
constexpr float INV_SQRT32 = 0.17677669529663687f;
constexpr float INV_SQRT96 = 0.10206207261596575f;
constexpr float INV_SQRT3  = 0.5773502691896258f;

// ---------------- histogram of edge_dst ----------------
__global__ void hist_kernel(const int* __restrict__ edst, int* __restrict__ cnt, int E){
    int e = blockIdx.x*blockDim.x + threadIdx.x;
    if (e < E) atomicAdd(&cnt[edst[e]], 1);
}

// ---------------- single-block exclusive scan ----------------
__global__ void scan_kernel(const int* __restrict__ cnt, int* __restrict__ row_start,
                            int* __restrict__ cursor, int n, int E){
    __shared__ int part[1024];
    const int t = threadIdx.x;
    const int C = (n + 1023) / 1024;
    int local[32];
    int base = t*C;
    int s = 0;
    for (int j = 0; j < C && j < 32; ++j){
        int idx = base + j;
        int v = (idx < n) ? cnt[idx] : 0;
        local[j] = s; s += v;
    }
    part[t] = s;
    __syncthreads();
    for (int off = 1; off < 1024; off <<= 1){
        int v = (t >= off) ? part[t-off] : 0;
        __syncthreads();
        part[t] += v;
        __syncthreads();
    }
    int pre = (t == 0) ? 0 : part[t-1];
    for (int j = 0; j < C && j < 32; ++j){
        int idx = base + j;
        if (idx < n){ int rs = pre + local[j]; row_start[idx] = rs; cursor[idx] = rs; }
    }
    if (t == 0) row_start[n] = E;
}

// ---------------- scatter: perm + sorted eattr/esrc sidecars ----------------
__global__ void scatter_kernel(const int* __restrict__ edst, const int* __restrict__ esrc,
                               const float4* __restrict__ eattr,
                               int* __restrict__ cursor, int* __restrict__ perm,
                               float4* __restrict__ eattr_s, int* __restrict__ esrc_s, int E){
    int e = blockIdx.x*blockDim.x + threadIdx.x;
    if (e < E){
        int p = atomicAdd(&cursor[edst[e]], 1);
        perm[p] = e; eattr_s[p] = eattr[e]; esrc_s[p] = esrc[e];
    }
}

__global__ void isd_kernel(const int* __restrict__ cnt, float* __restrict__ isd, int n){
    int i = blockIdx.x*blockDim.x + threadIdx.x;
    if (i < n) isd[i] = rsqrtf((float)cnt[i]);
}

// ---------------- weight prep: f32 -> f16, transpose, pad, fold 1/8 ----------------
__global__ void wprep(const float* __restrict__ Wfa1, const float* __restrict__ Wfb1,
                      const float* __restrict__ Wfa2, const float* __restrict__ Wfb2,
                      __half* __restrict__ Wc1, __half* __restrict__ Wc2){
    int t = blockIdx.x*blockDim.x + threadIdx.x;
    if (t < 64*WPAD){
        int c = t / WPAD, k = t - c*WPAD;
        float v1 = (k < 64) ? Wfa1[k*64 + c]*INV8 : 0.f;
        float v2 = (k < 64) ? Wfa2[k*64 + c]*INV8 : 0.f;
        Wc1[t] = __float2half(v1); Wc2[t] = __float2half(v2);
    } else if (t < 64*WPAD + 192*WPAD){
        int q = t - 64*WPAD; int o = q / WPAD, k = q - o*WPAD;
        float v1 = (k < 64) ? Wfb1[k*192 + o]*INV8 : 0.f;
        float v2 = (k < 64) ? Wfb2[k*192 + o]*INV8 : 0.f;
        Wc1[t] = __float2half(v1); Wc2[t] = __float2half(v2);
    }
}

// ---------------- tiled node pre-transform (8 nodes/block) ----------------
template<int OS>
__global__ __launch_bounds__(384) void node_pre_tiled(
    const float* __restrict__ s, int ss,
    const float* __restrict__ v, int vs,
    const float* __restrict__ attr,
    const float* __restrict__ Wl1s, const float* __restrict__ Wscs,
    const float* __restrict__ Wl1v, const float* __restrict__ Wscv,
    float* __restrict__ f_s, float* __restrict__ sc_s,
    float* __restrict__ f_v, float* __restrict__ sc_v, int N)
{
    constexpr int TOT = 64 + OS + 192;
    __shared__ __align__(16) float sA[8][160];
    __shared__ float s_at[8];
    const int t = threadIdx.x;
    const int n0 = blockIdx.x*8;
    const int nmax = min(8, N - n0);

    for (int idx = t; idx < 8*64; idx += 384){
        int n = idx >> 6, k = idx & 63;
        if (n < nmax) sA[n][k] = s[(size_t)(n0+n)*ss + k];
    }
    for (int idx = t; idx < 8*96; idx += 384){
        int n = idx/96, k = idx - n*96;
        if (n < nmax) sA[n][64 + k] = v[(size_t)(n0+n)*vs + k];
    }
    if (t < nmax) s_at[t] = attr[n0 + t];
    __syncthreads();

    if (t >= TOT) return;
    float acc[8] = {0,0,0,0,0,0,0,0};

    if (t < 64 + OS){
        const float* bp; int bstr;
        if (t < 64){ bp = Wl1s + t; bstr = 64; }
        else       { bp = Wscs + (t-64); bstr = OS; }
        #pragma unroll 4
        for (int k4 = 0; k4 < 64; k4 += 4){
            float b0 = bp[(size_t)(k4+0)*bstr], b1 = bp[(size_t)(k4+1)*bstr];
            float b2 = bp[(size_t)(k4+2)*bstr], b3 = bp[(size_t)(k4+3)*bstr];
            #pragma unroll
            for (int n = 0; n < 8; ++n){
                float4 a = *reinterpret_cast<const float4*>(&sA[n][k4]);
                acc[n] += a.x*b0 + a.y*b1 + a.z*b2 + a.w*b3;
            }
        }
        if (t < 64){
            #pragma unroll
            for (int n = 0; n < 8; ++n) if (n < nmax)
                f_s[(size_t)(n0+n)*64 + t] = acc[n]*s_at[n]*INV8;
        } else {
            int j = t - 64;
            #pragma unroll
            for (int n = 0; n < 8; ++n) if (n < nmax)
                sc_s[(size_t)(n0+n)*OS + j] = acc[n]*s_at[n]*INV8;
        }
    } else {
        int q = t - (64 + OS);
        bool first = (q < 96);
        int q2 = first ? q : q - 96;
        int w = q2/3, c = q2 - 3*w;
        const float* W = first ? Wl1v : Wscv;
        #pragma unroll 4
        for (int k = 0; k < 32; ++k){
            float b = W[k*32 + w];
            #pragma unroll
            for (int n = 0; n < 8; ++n) acc[n] += sA[n][64 + k*3 + c]*b;
        }
        float* op = first ? f_v : sc_v;
        #pragma unroll
        for (int n = 0; n < 8; ++n) if (n < nmax)
            op[(size_t)(n0+n)*96 + q2] = acc[n]*s_at[n]*INV_SQRT32;
    }
}

// ---------------- FUSED edge MLP (MFMA) + aggregation ----------------
// Block owns nodes [n0, n0+NB); loops 64-slot chunks of its sorted range.
// Phase 1: MFMA computes w-tile -> LDS wT[192][WT_STR] (channel-major).
// Phase 2: per-thread channel roles accumulate acc[NB] with 4-deep batching.
// Roles: r1 = tid (0..255, all mode0: A t<64, C otherwise);
//        r2 = 256+tid (tid<96: D mode2; 96<=tid<128: B mode1/dot3).
__global__ __launch_bounds__(256) void edge_fused(
    const int* __restrict__ row_start, const int* __restrict__ perm,
    const float* __restrict__ escal,
    const int* __restrict__ esrc_s, const float4* __restrict__ eattr_s,
    const __half* __restrict__ Wc,
    const float* __restrict__ f_s, const float* __restrict__ f_v,
    float* __restrict__ aggs, float* __restrict__ aggv, int N, int E)
{
    __shared__ __half lWa[64*WPAD];       // 9.2 KB
    __shared__ __half lWb[192*WPAD];      // 27.6 KB
    __shared__ __half hsm[4][16*WPAD];    // 9.2 KB
    __shared__ __align__(8) __half wT[192*WT_STR];  // 26.1 KB
    __shared__ int   s_src[64];
    __shared__ float s_ea[4][64];
    __shared__ int   s_rs[NB+1];

    const int tid = threadIdx.x;
    // stage MLP weights
    {
        const uint4* src4 = reinterpret_cast<const uint4*>(Wc);
        uint4* dA = reinterpret_cast<uint4*>(lWa);
        uint4* dB = reinterpret_cast<uint4*>(lWb);
        for (int i = tid; i < (64*WPAD)/8; i += 256) dA[i] = src4[i];
        for (int i = tid; i < (192*WPAD)/8; i += 256) dB[i] = src4[(64*WPAD)/8 + i];
    }
    const int n0 = blockIdx.x*NB;
    const int nmax = min(NB, N - n0);
    for (int idx = tid; idx <= NB; idx += 256)
        s_rs[idx] = row_start[min(n0 + idx, N)];
    const int rs0 = row_start[n0];
    const int re0 = row_start[n0 + nmax];

    const int wv = tid >> 6, l = tid & 63;
    const int lm = l & 15, kg = l >> 4;

    // role decode (fixed per thread)
    const int widx1 = (tid < 64) ? tid : 64 + ((tid-64) & 63);
    const int fidx1 = (tid < 64) ? tid : ((tid-64) & 63);
    const int eac1  = (tid < 64) ? 0 : 1 + ((tid-64) >> 6);
    const bool isD = (tid < 96);                  // role2 mode2
    const bool isB = (tid >= 96 && tid < 128);    // role2 mode1
    const int cD = tid >> 5, uD = tid & 31;       // valid when isD
    const int uB = tid - 96;                      // valid when isB
    const int widx2 = isD ? (128 + uD) : (160 + uB);
    const int fidx2 = isD ? (3*uD + cD) : (3*uB);

    float a1[NB], a2[NB];
    #pragma unroll
    for (int nn = 0; nn < NB; ++nn){ a1[nn] = 0.f; a2[nn] = 0.f; }

    for (int c0 = rs0; c0 < re0; c0 += 64){
        const int m = min(64, re0 - c0);
        __syncthreads();                  // previous chunk's readers done
        if (tid < m){
            s_src[tid] = esrc_s[c0 + tid];
            float4 ea = eattr_s[c0 + tid];
            s_ea[0][tid] = ea.x; s_ea[1][tid] = ea.y;
            s_ea[2][tid] = ea.z; s_ea[3][tid] = ea.w;
        }

        // ---- Phase 1: MFMA w-tile ----
        int slot = c0 + wv*16 + lm; if (slot >= E) slot = E - 1;
        const int e = perm[slot];
        const float* xp = escal + (size_t)e*64 + kg*8;
        f16x8 xf0, xf1;
        {
            float4 q0 = *reinterpret_cast<const float4*>(xp);
            float4 q1 = *reinterpret_cast<const float4*>(xp + 4);
            float4 q2 = *reinterpret_cast<const float4*>(xp + 32);
            float4 q3 = *reinterpret_cast<const float4*>(xp + 36);
            xf0[0]=(_Float16)q0.x; xf0[1]=(_Float16)q0.y; xf0[2]=(_Float16)q0.z; xf0[3]=(_Float16)q0.w;
            xf0[4]=(_Float16)q1.x; xf0[5]=(_Float16)q1.y; xf0[6]=(_Float16)q1.z; xf0[7]=(_Float16)q1.w;
            xf1[0]=(_Float16)q2.x; xf1[1]=(_Float16)q2.y; xf1[2]=(_Float16)q2.z; xf1[3]=(_Float16)q2.w;
            xf1[4]=(_Float16)q3.x; xf1[5]=(_Float16)q3.y; xf1[6]=(_Float16)q3.z; xf1[7]=(_Float16)q3.w;
        }

        #pragma unroll
        for (int nt = 0; nt < 4; ++nt){
            f16x8 wa0 = *reinterpret_cast<const f16x8*>(&lWa[(nt*16 + lm)*WPAD + kg*8]);
            f16x8 wa1 = *reinterpret_cast<const f16x8*>(&lWa[(nt*16 + lm)*WPAD + 32 + kg*8]);
            f32x4 acc = {0.f,0.f,0.f,0.f};
            acc = __builtin_amdgcn_mfma_f32_16x16x32_f16(xf0, wa0, acc, 0, 0, 0);
            acc = __builtin_amdgcn_mfma_f32_16x16x32_f16(xf1, wa1, acc, 0, 0, 0);
            #pragma unroll
            for (int r = 0; r < 4; ++r)
                hsm[wv][(kg*4 + r)*WPAD + nt*16 + lm] = __float2half(siluf(acc[r]));
        }
        // hsm is wave-private (hsm[wv]); no barrier needed before read
        f16x8 ha0 = *reinterpret_cast<const f16x8*>(&hsm[wv][lm*WPAD + kg*8]);
        f16x8 ha1 = *reinterpret_cast<const f16x8*>(&hsm[wv][lm*WPAD + 32 + kg*8]);
        const int srow = wv*16 + kg*4;     // local slot of acc[0]
        #pragma unroll 4
        for (int nt = 0; nt < 12; ++nt){
            f16x8 wb0 = *reinterpret_cast<const f16x8*>(&lWb[(nt*16 + lm)*WPAD + kg*8]);
            f16x8 wb1 = *reinterpret_cast<const f16x8*>(&lWb[(nt*16 + lm)*WPAD + 32 + kg*8]);
            f32x4 acc = {0.f,0.f,0.f,0.f};
            acc = __builtin_amdgcn_mfma_f32_16x16x32_f16(ha0, wb0, acc, 0, 0, 0);
            acc = __builtin_amdgcn_mfma_f32_16x16x32_f16(ha1, wb1, acc, 0, 0, 0);
            union { __half2 h2[2]; uint2 u; } pk;
            pk.h2[0] = __floats2half2_rn(acc[0], acc[1]);
            pk.h2[1] = __floats2half2_rn(acc[2], acc[3]);
            *reinterpret_cast<uint2*>(&wT[(nt*16 + lm)*WT_STR + srow]) = pk.u;
        }
        __syncthreads();                  // wT + s_src ready

        // ---- Phase 2: aggregation over per-node segments ----
        #pragma unroll
        for (int nn = 0; nn < NB; ++nn){
            int lo = max(s_rs[nn], c0) - c0;
            int hi = min(s_rs[nn+1], c0 + m) - c0;
            if (lo >= hi) continue;
            float v1 = a1[nn], v2 = a2[nn];
            int i = lo;
            for (; i + 4 <= hi; i += 4){
                int s0 = s_src[i+0], s1 = s_src[i+1], s2 = s_src[i+2], s3 = s_src[i+3];
                float w10 = __half2float(wT[widx1*WT_STR + i+0]);
                float w11 = __half2float(wT[widx1*WT_STR + i+1]);
                float w12 = __half2float(wT[widx1*WT_STR + i+2]);
                float w13 = __half2float(wT[widx1*WT_STR + i+3]);
                float g10 = f_s[(size_t)s0*64 + fidx1];
                float g11 = f_s[(size_t)s1*64 + fidx1];
                float g12 = f_s[(size_t)s2*64 + fidx1];
                float g13 = f_s[(size_t)s3*64 + fidx1];
                v1 += w10*g10*s_ea[eac1][i+0] + w11*g11*s_ea[eac1][i+1]
                    + w12*g12*s_ea[eac1][i+2] + w13*g13*s_ea[eac1][i+3];
                if (isD){
                    float w20 = __half2float(wT[widx2*WT_STR + i+0]);
                    float w21 = __half2float(wT[widx2*WT_STR + i+1]);
                    float w22 = __half2float(wT[widx2*WT_STR + i+2]);
                    float w23 = __half2float(wT[widx2*WT_STR + i+3]);
                    float g20 = f_v[(size_t)s0*96 + fidx2];
                    float g21 = f_v[(size_t)s1*96 + fidx2];
                    float g22 = f_v[(size_t)s2*96 + fidx2];
                    float g23 = f_v[(size_t)s3*96 + fidx2];
                    v2 += w20*g20*s_ea[0][i+0] + w21*g21*s_ea[0][i+1]
                        + w22*g22*s_ea[0][i+2] + w23*g23*s_ea[0][i+3];
                } else if (isB){
                    float w20 = __half2float(wT[widx2*WT_STR + i+0]);
                    float w21 = __half2float(wT[widx2*WT_STR + i+1]);
                    float w22 = __half2float(wT[widx2*WT_STR + i+2]);
                    float w23 = __half2float(wT[widx2*WT_STR + i+3]);
                    const float* p0 = f_v + (size_t)s0*96 + fidx2;
                    const float* p1 = f_v + (size_t)s1*96 + fidx2;
                    const float* p2 = f_v + (size_t)s2*96 + fidx2;
                    const float* p3 = f_v + (size_t)s3*96 + fidx2;
                    float d0 = p0[0]*s_ea[1][i+0] + p0[1]*s_ea[2][i+0] + p0[2]*s_ea[3][i+0];
                    float d1 = p1[0]*s_ea[1][i+1] + p1[1]*s_ea[2][i+1] + p1[2]*s_ea[3][i+1];
                    float d2 = p2[0]*s_ea[1][i+2] + p2[1]*s_ea[2][i+2] + p2[2]*s_ea[3][i+2];
                    float d3 = p3[0]*s_ea[1][i+3] + p3[1]*s_ea[2][i+3] + p3[2]*s_ea[3][i+3];
                    v2 += w20*d0 + w21*d1 + w22*d2 + w23*d3;
                }
            }
            for (; i < hi; ++i){
                int s0 = s_src[i];
                float w1 = __half2float(wT[widx1*WT_STR + i]);
                v1 += w1 * f_s[(size_t)s0*64 + fidx1] * s_ea[eac1][i];
                if (isD){
                    float w2 = __half2float(wT[widx2*WT_STR + i]);
                    v2 += w2 * f_v[(size_t)s0*96 + fidx2] * s_ea[0][i];
                } else if (isB){
                    float w2 = __half2float(wT[widx2*WT_STR + i]);
                    const float* p = f_v + (size_t)s0*96 + fidx2;
                    float d = p[0]*s_ea[1][i] + p[1]*s_ea[2][i] + p[2]*s_ea[3][i];
                    v2 += w2 * d;
                }
            }
            a1[nn] = v1; a2[nn] = v2;
        }
    }

    // ---- write-out ----
    const size_t N96 = (size_t)N*96;
    #pragma unroll
    for (int nn = 0; nn < NB; ++nn){
        if (nn < nmax){
            const int gn = n0 + nn;
            if (tid < 64) aggs[(size_t)gn*96 + tid] = a1[nn];
            else aggv[(size_t)(eac1-1)*N96 + (size_t)gn*96 + fidx1] = a1[nn];
            if (isD) aggv[(size_t)cD*N96 + (size_t)gn*96 + 64 + uD] = a2[nn];
            else if (isB) aggs[(size_t)gn*96 + 64 + uB] = a2[nn]*INV_SQRT3;
        }
    }
}

// ---------------- tiled fused post: GEMM (8 nodes/block) + mix ----------------
template<int OS, bool FINAL>
__global__ __launch_bounds__(256) void post_fused(
    const float* __restrict__ aggs, const float* __restrict__ aggv,
    const float* __restrict__ W2s, const float* __restrict__ W2v,
    const float* __restrict__ W3,
    const float* __restrict__ isd, const float* __restrict__ attr,
    const float* __restrict__ sc_s, const float* __restrict__ sc_v,
    float* __restrict__ out_s, float* __restrict__ out_v, int N)
{
    constexpr int TOTC = OS + 1 + 96;
    constexpr int PSTR = 96*8 + 8;
    __shared__ __align__(16) float s_a[4*PSTR];
    __shared__ float s_pre[8][TOTC];

    const int t = threadIdx.x;
    const int n0 = blockIdx.x*8;
    const int nmax = min(8, N - n0);
    const size_t N96 = (size_t)N*96;

    for (int idx = t; idx < 8*96; idx += 256){
        int n = idx/96, k = idx - n*96;
        if (n < nmax) s_a[k*8 + n] = aggs[(size_t)(n0+n)*96 + k];
    }
    for (int idx = t; idx < 3*8*96; idx += 256){
        int p = idx/768, rem = idx - p*768;
        int n = rem/96, k = rem - n*96;
        if (n < nmax) s_a[(1+p)*PSTR + k*8 + n] = aggv[(size_t)p*N96 + (size_t)(n0+n)*96 + k];
    }
    __syncthreads();

    if (t < TOTC){
        const float* bp; int bstr; int plane;
        if (t < OS){ bp = W2s + t; bstr = OS; plane = 0; }
        else if (t == OS){ bp = W3; bstr = 1; plane = 0; }
        else { int q = t - OS - 1; int cv = q>>5, ww = q&31; bp = W2v + ww; bstr = 32; plane = 1+cv; }
        const float* ap = &s_a[plane*PSTR];

        float acc0=0,acc1=0,acc2=0,acc3=0,acc4=0,acc5=0,acc6=0,acc7=0;
        #pragma unroll 4
        for (int k = 0; k < 96; ++k){
            float b = bp[(size_t)k*bstr];
            float4 q0 = *reinterpret_cast<const float4*>(ap + k*8);
            float4 q1 = *reinterpret_cast<const float4*>(ap + k*8 + 4);
            acc0 += q0.x*b; acc1 += q0.y*b; acc2 += q0.z*b; acc3 += q0.w*b;
            acc4 += q1.x*b; acc5 += q1.y*b; acc6 += q1.z*b; acc7 += q1.w*b;
        }
        s_pre[0][t]=acc0; s_pre[1][t]=acc1; s_pre[2][t]=acc2; s_pre[3][t]=acc3;
        s_pre[4][t]=acc4; s_pre[5][t]=acc5; s_pre[6][t]=acc6; s_pre[7][t]=acc7;
    }
    __syncthreads();

    for (int idx = t; idx < nmax*192; idx += 256){
        int n = idx/192, r = idx - n*192;
        int gn = n0 + n;
        float sca = isd[gn]*attr[gn]*INV_SQRT96;
        float ang = 0.1f * s_pre[n][OS] * sca;
        float c_ = cosf(ang), s_ = sinf(ang);
        if (r < OS){
            float hs = c_*sc_s[(size_t)gn*OS + r] + s_*s_pre[n][r]*sca;
            if (FINAL) out_s[(size_t)gn*160 + r] = hs;
            else if (r < 64) out_s[(size_t)gn*64 + r] = siluf(hs);
        } else if (r >= 96){
            int q2 = r - 96;
            int ww = q2/3, c2 = q2 - 3*ww;
            float hv = c_*sc_v[(size_t)gn*96 + q2] + s_*s_pre[n][OS+1 + c2*32 + ww]*sca;
            if (FINAL){
                out_s[(size_t)gn*160 + 64 + q2] = hv;
            } else {
                float hs64 = c_*sc_s[(size_t)gn*OS + 64 + ww] + s_*s_pre[n][64 + ww]*sca;
                float sg = 1.f/(1.f + __expf(-hs64));
                out_v[(size_t)gn*96 + q2] = sg*hv;
            }
        }
    }
}

// ---------------- launch ----------------
extern "C" void kernel_launch(void* const* d_in, const int* in_sizes, int n_in,
                              void* d_out, int out_size, void* d_ws, size_t ws_size,
                              hipStream_t stream)
{
    const float* nf    = (const float*)d_in[0];
    const float* nattr = (const float*)d_in[1];
    const int*   esrc  = (const int*)  d_in[2];
    const int*   edst  = (const int*)  d_in[3];
    const float* eattr = (const float*)d_in[4];
    const float* escal = (const float*)d_in[5];
    const float* p1_sc_s = (const float*)d_in[6];
    const float* p1_sc_v = (const float*)d_in[7];
    const float* p1_l1_s = (const float*)d_in[8];
    const float* p1_l1_v = (const float*)d_in[9];
    const float* p1_fa   = (const float*)d_in[10];
    const float* p1_fb   = (const float*)d_in[11];
    const float* p1_l2_s = (const float*)d_in[12];
    const float* p1_l2_v = (const float*)d_in[13];
    const float* p1_l3   = (const float*)d_in[14];
    const float* p2_sc_s = (const float*)d_in[15];
    const float* p2_sc_v = (const float*)d_in[16];
    const float* p2_l1_s = (const float*)d_in[17];
    const float* p2_l1_v = (const float*)d_in[18];
    const float* p2_fa   = (const float*)d_in[19];
    const float* p2_fb   = (const float*)d_in[20];
    const float* p2_l2_s = (const float*)d_in[21];
    const float* p2_l2_v = (const float*)d_in[22];
    const float* p2_l3   = (const float*)d_in[23];

    const int N = in_sizes[1];
    const int E = in_sizes[2];

    // ---- workspace layout ----
    char* wsb = (char*)d_ws;
    float4* eattr_s = (float4*)wsb;   wsb += (size_t)E*16;
    __half* Wc1 = (__half*)wsb;       wsb += (size_t)(256*WPAD)*2;
    __half* Wc2 = (__half*)wsb;       wsb += (size_t)(256*WPAD)*2;
    float* fs   = (float*)wsb;        wsb += (size_t)N*64*4;
    float* fv   = (float*)wsb;        wsb += (size_t)N*96*4;
    float* scs  = (float*)wsb;        wsb += (size_t)N*96*4;
    float* scv  = (float*)wsb;        wsb += (size_t)N*96*4;
    float* gs   = (float*)wsb;        wsb += (size_t)N*64*4;
    float* gv   = (float*)wsb;        wsb += (size_t)N*96*4;
    float* aggs = (float*)wsb;        wsb += (size_t)N*96*4;
    float* aggv = (float*)wsb;        wsb += (size_t)N*96*3*4;
    float* isd  = (float*)wsb;        wsb += (size_t)N*4;
    int* cnt       = (int*)wsb;       wsb += (size_t)N*4;
    int* row_start = (int*)wsb;       wsb += (size_t)(N+1)*4;
    int* cursor    = (int*)wsb;       wsb += (size_t)N*4;
    int* perm      = (int*)wsb;       wsb += (size_t)E*4;
    int* esrc_s    = (int*)wsb;       wsb += (size_t)E*4;

    // ---- sort edges by dst + weight prep ----
    hipMemsetAsync(cnt, 0, (size_t)N*4, stream);
    hist_kernel<<<(E+255)/256, 256, 0, stream>>>(edst, cnt, E);
    scan_kernel<<<1, 1024, 0, stream>>>(cnt, row_start, cursor, N, E);
    scatter_kernel<<<(E+255)/256, 256, 0, stream>>>(edst, esrc, (const float4*)eattr,
                                                    cursor, perm, eattr_s, esrc_s, E);
    isd_kernel<<<(N+255)/256, 256, 0, stream>>>(cnt, isd, N);
    wprep<<<(256*WPAD+255)/256, 256, 0, stream>>>(p1_fa, p1_fb, p2_fa, p2_fb, Wc1, Wc2);

    const int tile_grid  = (N + 7)/8;
    const int fused_grid = (N + NB - 1)/NB;

    // ---- conv1 ----
    node_pre_tiled<96><<<tile_grid, 384, 0, stream>>>(nf, 160, nf+64, 160, nattr,
        p1_l1_s, p1_sc_s, p1_l1_v, p1_sc_v, fs, scs, fv, scv, N);
    edge_fused<<<fused_grid, 256, 0, stream>>>(row_start, perm, escal,
        esrc_s, eattr_s, Wc1, fs, fv, aggs, aggv, N, E);
    post_fused<96, false><<<tile_grid, 256, 0, stream>>>(aggs, aggv,
        p1_l2_s, p1_l2_v, p1_l3, isd, nattr, scs, scv, gs, gv, N);

    // ---- conv2 ----
    node_pre_tiled<64><<<tile_grid, 384, 0, stream>>>(gs, 64, gv, 96, nattr,
        p2_l1_s, p2_sc_s, p2_l1_v, p2_sc_v, fs, scs, fv, scv, N);
    edge_fused<<<fused_grid, 256, 0, stream>>>(row_start, perm, escal,
        esrc_s, eattr_s, Wc2, fs, fv, aggs, aggv, N, E);
    post_fused<64, true><<<tile_grid, 256, 0, stream>>>(aggs, aggv,
        p2_l2_s, p2_l2_v, p2_l3, isd, nattr, scs, scv, (float*)d_out, nullptr, N);
}